// Round 2
// baseline (155.776 us; speedup 1.0000x reference)
//
#include <hip/hip_runtime.h>
#include <hip/hip_bf16.h>
#include <stdint.h>

typedef short  short8  __attribute__((ext_vector_type(8)));
typedef float  floatx4 __attribute__((ext_vector_type(4)));

// ---------------- main fused kernel ----------------
__device__ __forceinline__ floatx4 mfma16(short8 a, short8 b, floatx4 c) {
    return __builtin_amdgcn_mfma_f32_16x16x32_bf16(a, b, c, 0, 0, 0);
}

__device__ __forceinline__ unsigned packbf2(float lo, float hi) {
    union { __hip_bfloat162 b2; unsigned u; } c;
    c.b2 = __float22bfloat162_rn(make_float2(lo, hi));
    return c.u;
}

__device__ __forceinline__ short8 pack8(floatx4 a, floatx4 b) {
    union { unsigned u[4]; short8 s; } r;
    r.u[0] = packbf2(a[0], a[1]);
    r.u[1] = packbf2(a[2], a[3]);
    r.u[2] = packbf2(b[0], b[1]);
    r.u[3] = packbf2(b[2], b[3]);
    return r.s;
}

// Write one layer's relu'd output (8 feature-tiles, full 16B chunks) for this
// lane's 4 rows. h layout: row m (16 rows) x 16 chunks of 16B; chunk c of row
// m stored at chunk' = c ^ (m&15).
__device__ __forceinline__ void write_h_b128(char* hb, int q, int ln,
                                             const floatx4* acc) {
    #pragma unroll
    for (int r = 0; r < 4; ++r) {
        const int m = q * 4 + r;
        union { unsigned u[4]; short8 s; } pk;
        #pragma unroll
        for (int j = 0; j < 4; ++j)
            pk.u[j] = packbf2(fmaxf(acc[2 * j][r], 0.0f), fmaxf(acc[2 * j + 1][r], 0.0f));
        const int cp = ln ^ (m & 15);
        *(short8*)(hb + m * 256 + cp * 16) = pk.s;
    }
}

// n-split variant: this wave owns features nt_glob = half*4 + (0..3), i.e. the
// bytes [half*8, half*8+8) of each swizzled 16B chunk (chunk packs feats
// {k*16+ln, k=0..7} as bf16 pairs). Writes 8B per row -> ds_write_b64.
__device__ __forceinline__ void write_h_b64_half(char* hb, int q, int ln, int half,
                                                 const floatx4* acc) {
    #pragma unroll
    for (int r = 0; r < 4; ++r) {
        const int m = q * 4 + r;
        uint2 pk;
        pk.x = packbf2(fmaxf(acc[0][r], 0.0f), fmaxf(acc[1][r], 0.0f));
        pk.y = packbf2(fmaxf(acc[2][r], 0.0f), fmaxf(acc[3][r], 0.0f));
        const int cp = ln ^ (m & 15);
        *(uint2*)(hb + m * 256 + cp * 16 + half * 8) = pk;
    }
}

__device__ __forceinline__ void read_a_b128(const char* hb, int q, int ln, short8* a) {
    #pragma unroll
    for (int s2 = 0; s2 < 4; ++s2) {
        const int cp = (s2 * 4 + q) ^ (ln & 15);
        a[s2] = *(const short8*)(hb + ln * 256 + cp * 16);
    }
}

__device__ __forceinline__ void mat3mul(float* C, const float* A, const float* B) {
    #pragma unroll
    for (int i = 0; i < 3; ++i)
        #pragma unroll
        for (int j = 0; j < 3; ++j)
            C[i*3+j] = A[i*3+0]*B[0+j] + A[i*3+1]*B[3+j] + A[i*3+2]*B[6+j];
}

// Wave layout: wv0,1 = rot pair, wv2,3 = trz pair. A pair processes all 256
// rows of the WG together, 32 rows per iteration (wave `half` does L0/L2 for
// its own 16-row group). L1 is feature-split: each wave holds only HALF of W1
// (16 short8 = 64 VGPRs instead of 128) and computes its 64 output features
// for BOTH groups; halves are merged through the swizzled lds_h chunks.
//
// NO WORKSPACE: weight fragments are gathered directly from the original fp32
// arrays in the prologue (sigma element j of fragment (n,s2,q) is
// W[n][j*16 + s2*4 + q], a stride-16 gather). ~190 one-time loads per wave,
// L2-resident across the grid (90 KB total weights). This removes prep_kernel
// AND all d_ws use -- targeting the two 256 MiB workspace poison-fills that
// account for 85 of the 115 us.
__launch_bounds__(256, 2)
__global__ void fused_main(const float* __restrict__ y,
                           const float* __restrict__ ow0, const float* __restrict__ ob0,
                           const float* __restrict__ ow1, const float* __restrict__ ob1,
                           const float* __restrict__ ow2, const float* __restrict__ ob2,
                           const float* __restrict__ tw0, const float* __restrict__ tb0,
                           const float* __restrict__ tw1, const float* __restrict__ tb1,
                           const float* __restrict__ tw2, const float* __restrict__ tb2,
                           float* __restrict__ out)
{
    // [mlp][phase(h1/h2)][group][16 rows x 256B]
    __shared__ __align__(16) unsigned char lds_h[2][2][2][4096];
    __shared__ __align__(16) float lds_stage[256 * 12];    // per-row [9 omega | 3 trz]

    const int tid  = threadIdx.x;
    const int wv   = tid >> 6;
    const int lane = tid & 63;
    const int ln   = lane & 15;
    const int q    = lane >> 4;
    const int mlp  = wv >> 1;   // 0 = rot, 1 = trz
    const int half = wv & 1;    // feature half for L1, row group for L0/L2
    const int wgbase = blockIdx.x * 256;

    const float* w0p = mlp ? tw0 : ow0;
    const float* w1p = mlp ? tw1 : ow1;
    const float* w2p = mlp ? tw2 : ow2;
    const float* b0p = mlp ? tb0 : ob0;
    const float* b1p = mlp ? tb1 : ob1;
    const float* b2p = mlp ? tb2 : ob2;
    const int nvalid = mlp ? 3 : 9;

    // y addressing: row = wgbase + iter*32 + half*16 + ln, col = mlp*32 + q*8
    const float* ybase = y + (size_t)(wgbase + half * 16 + ln) * 64 + mlp * 32 + q * 8;

    // issue the first y prefetches before the weight gather so HBM latency of
    // both overlaps
    floatx4 c00 = *(const floatx4*)(ybase);
    floatx4 c01 = *(const floatx4*)(ybase + 4);
    floatx4 c10 = *(const floatx4*)(ybase + 2048);
    floatx4 c11 = *(const floatx4*)(ybase + 2052);

    // ---- persistent B-fragments: 8 + 16 + 4 = 28 short8 = 112 regs ----
    short8 bw0[8], bw1[16], bw2[4];
    #pragma unroll
    for (int nt = 0; nt < 8; ++nt) {       // W0 [128][32] natural, contiguous 8
        const float* p = w0p + (nt * 16 + ln) * 32 + q * 8;
        floatx4 lo = *(const floatx4*)p;
        floatx4 hi = *(const floatx4*)(p + 4);
        bw0[nt] = pack8(lo, hi);
    }
    #pragma unroll
    for (int nt = 0; nt < 4; ++nt) {       // W1 [128][128], stride-16 gather
        const float* rowp = w1p + ((half * 4 + nt) * 16 + ln) * 128;
        #pragma unroll
        for (int s2 = 0; s2 < 4; ++s2) {
            const int c = s2 * 4 + q;
            floatx4 lo, hi;
            #pragma unroll
            for (int j = 0; j < 4; ++j) lo[j] = rowp[j * 16 + c];
            #pragma unroll
            for (int j = 0; j < 4; ++j) hi[j] = rowp[(j + 4) * 16 + c];
            bw1[nt * 4 + s2] = pack8(lo, hi);
        }
    }
    {                                       // W2 [nvalid][128], rows >= nvalid are zero
        const bool vrow = (ln < nvalid);
        const float* rowp = w2p + ln * 128;
        #pragma unroll
        for (int s2 = 0; s2 < 4; ++s2) {
            const int c = s2 * 4 + q;
            floatx4 lo, hi;
            #pragma unroll
            for (int j = 0; j < 4; ++j) lo[j] = vrow ? rowp[j * 16 + c] : 0.0f;
            #pragma unroll
            for (int j = 0; j < 4; ++j) hi[j] = vrow ? rowp[(j + 4) * 16 + c] : 0.0f;
            bw2[s2] = pack8(lo, hi);
        }
    }

    float b0v[8], b1v[4];
    #pragma unroll
    for (int nt = 0; nt < 8; ++nt) b0v[nt] = b0p[nt * 16 + ln];
    #pragma unroll
    for (int nt = 0; nt < 4; ++nt) b1v[nt] = b1p[(half * 4 + nt) * 16 + ln];
    const float b2v = (ln < nvalid) ? b2p[ln] : 0.0f;

    char* const hbase   = (char*)&lds_h[mlp][0][0][0];
    char* const h0_mine = hbase + half * 4096;            // h1 buffer, my group
    char* const h1_mine = hbase + 8192 + half * 4096;     // h2 buffer, my group

    const int cb = mlp ? 9 : 0;

    auto body = [&](int iter, short8 a0) {
        // ---- layer 0 (row-split: my 16 rows, full 128 features) ----
        floatx4 acc0[8];
        #pragma unroll
        for (int nt = 0; nt < 8; ++nt) {
            const float b = b0v[nt];
            floatx4 c = {b, b, b, b};
            acc0[nt] = mfma16(a0, bw0[nt], c);
        }
        write_h_b128(h0_mine, q, ln, acc0);
        __syncthreads();   // h1 complete (both groups)

        // ---- layer 1 (feature-split: my 64 features, both 16-row groups) ----
        floatx4 acc1[2][4];
        #pragma unroll
        for (int g2 = 0; g2 < 2; ++g2) {
            #pragma unroll
            for (int nt = 0; nt < 4; ++nt) {
                const float b = b1v[nt];
                floatx4 c = {b, b, b, b};
                acc1[g2][nt] = c;
            }
        }
        #pragma unroll
        for (int g2 = 0; g2 < 2; ++g2) {
            const char* src = hbase + g2 * 4096;
            #pragma unroll
            for (int s2 = 0; s2 < 4; ++s2) {
                const int cp = (s2 * 4 + q) ^ ln;
                short8 a1 = *(const short8*)(src + ln * 256 + cp * 16);
                #pragma unroll
                for (int nt = 0; nt < 4; ++nt)
                    acc1[g2][nt] = mfma16(a1, bw1[nt * 4 + s2], acc1[g2][nt]);
            }
        }
        #pragma unroll
        for (int g2 = 0; g2 < 2; ++g2)
            write_h_b64_half(hbase + 8192 + g2 * 4096, q, ln, half, acc1[g2]);
        __syncthreads();   // h2 complete (both halves merged)

        // ---- layer 2 (row-split: my 16 rows, 16 outputs) ----
        short8 a2[4];
        read_a_b128(h1_mine, q, ln, a2);
        floatx4 acc2 = {b2v, b2v, b2v, b2v};
        #pragma unroll
        for (int s2 = 0; s2 < 4; ++s2)
            acc2 = mfma16(a2[s2], bw2[s2], acc2);

        if (ln < nvalid) {
            const int rl = iter * 32 + half * 16 + q * 4;
            #pragma unroll
            for (int r = 0; r < 4; ++r)
                lds_stage[(rl + r) * 12 + cb + ln] = acc2[r];
        }
    };

    #pragma unroll 1
    for (int it2 = 0; it2 < 4; ++it2) {
        {
            short8 a0 = pack8(c00, c01);
            if (it2 < 3) {
                const float* p = ybase + (size_t)(it2 * 2 + 2) * 2048;
                c00 = *(const floatx4*)(p);
                c01 = *(const floatx4*)(p + 4);
            }
            body(it2 * 2, a0);
        }
        {
            short8 a0 = pack8(c10, c11);
            if (it2 < 3) {
                const float* p = ybase + (size_t)(it2 * 2 + 3) * 2048;
                c10 = *(const floatx4*)(p);
                c11 = *(const floatx4*)(p + 4);
            }
            body(it2 * 2 + 1, a0);
        }
    }

    __syncthreads();

    // ---- expm: one row per thread (256 rows/WG) ----
    {
        float* st = &lds_stage[tid * 12];
        floatx4 m0 = *(floatx4*)(st);
        floatx4 m1 = *(floatx4*)(st + 4);
        floatx4 m2 = *(floatx4*)(st + 8);
        float M[9] = {m0[0], m0[1], m0[2], m0[3], m1[0], m1[1], m1[2], m1[3], m2[0]};
        const float tz0 = m2[1], tz1 = m2[2], tz2 = m2[3];

        float r0 = fabsf(M[0]) + fabsf(M[1]) + fabsf(M[2]);
        float r1 = fabsf(M[3]) + fabsf(M[4]) + fabsf(M[5]);
        float r2 = fabsf(M[6]) + fabsf(M[7]) + fabsf(M[8]);
        float nrm = fmaxf(r0, fmaxf(r1, r2));
        int e; (void)frexpf(nrm, &e);
        int s = e + 1;
        if (s < 0) s = 0;
        if (s > 24) s = 24;
        float sc;
        { union { unsigned u; float f; } cv; cv.u = (unsigned)(127 - s) << 23; sc = cv.f; }
        #pragma unroll
        for (int i = 0; i < 9; ++i) M[i] *= sc;

        float Rm[9];
        #pragma unroll
        for (int i = 0; i < 9; ++i) Rm[i] = 0.0f;
        Rm[0] = Rm[4] = Rm[8] = 1.0f;
        #pragma unroll
        for (int j = 12; j >= 1; --j) {
            float T[9]; mat3mul(T, M, Rm);
            const float inv = 1.0f / (float)j;
            #pragma unroll
            for (int i = 0; i < 9; ++i) Rm[i] = T[i] * inv;
            Rm[0] += 1.0f; Rm[4] += 1.0f; Rm[8] += 1.0f;
        }
        for (int it = 0; it < s; ++it) {
            float T[9]; mat3mul(T, Rm, Rm);
            #pragma unroll
            for (int i = 0; i < 9; ++i) Rm[i] = T[i];
        }

        floatx4 o0 = {Rm[0], Rm[1], Rm[2], Rm[3]};
        floatx4 o1 = {Rm[4], Rm[5], Rm[6], Rm[7]};
        floatx4 o2 = {Rm[8], tz0, tz1, tz2};
        *(floatx4*)(st)     = o0;
        *(floatx4*)(st + 4) = o1;
        *(floatx4*)(st + 8) = o2;
    }

    __syncthreads();

    // ---- fully-coalesced output: 768 contiguous 16B chunks per WG ----
    {
        float* ob = out + (size_t)wgbase * 12;
        #pragma unroll
        for (int k = 0; k < 3; ++k) {
            const int j = k * 256 + tid;
            floatx4 v = *(floatx4*)&lds_stage[j * 4];
            *(floatx4*)(ob + j * 4) = v;
        }
    }
}

extern "C" void kernel_launch(void* const* d_in, const int* in_sizes, int n_in,
                              void* d_out, int out_size, void* d_ws, size_t ws_size,
                              hipStream_t stream)
{
    // NOTE: d_ws intentionally unused -- no workspace, no prep kernel.
    (void)d_ws; (void)ws_size;
    fused_main<<<512, 256, 0, stream>>>(
        (const float*)d_in[0],
        (const float*)d_in[1], (const float*)d_in[2],
        (const float*)d_in[3], (const float*)d_in[4],
        (const float*)d_in[5], (const float*)d_in[6],
        (const float*)d_in[7], (const float*)d_in[8],
        (const float*)d_in[9], (const float*)d_in[10],
        (const float*)d_in[11], (const float*)d_in[12],
        (float*)d_out);
}